// Round 1
// 344.631 us; speedup vs baseline: 1.0001x; 1.0001x over previous
//
#include <hip/hip_runtime.h>

#define NN 50000
#define NE 800000
#define FIN 128
#define H 64
#define NG 64
#define BN_EPS 1e-5f
#define INV_N (1.0f / 50000.0f)
#define NBKT 196  // dst buckets of 256 nodes

__device__ __forceinline__ void f4acc(float4& a, const float4 b) {
    a.x += b.x; a.y += b.y; a.z += b.z; a.w += b.w;
}

// ---------------- setup: zero slots/pool/bucket counters, transpose all W ----------------
__global__ void setup_misc(const float* __restrict__ W0, const float* __restrict__ W1,
                           const float* __restrict__ W2, float* __restrict__ Wt0,
                           float* __restrict__ Wt1, float* __restrict__ Wt2,
                           float* __restrict__ sl0, float* __restrict__ sl1,
                           float* __restrict__ sl2, float* __restrict__ poolcnt,
                           int* __restrict__ bktcnt) {
    int i = blockIdx.x * 256 + threadIdx.x;
    if (i < 64 * 128) { sl0[i] = 0.f; sl1[i] = 0.f; sl2[i] = 0.f; }
    if (i < NG * H + NG) poolcnt[i] = 0.f;
    if (i < NBKT) bktcnt[i] = 0;
    if (i < FIN * 64) {
        int k = i >> 6, o = i & 63;
        Wt0[i] = W0[o * FIN + k];
    }
    if (i < H * 64) {
        int k = i >> 6, o = i & 63;
        Wt1[i] = W1[o * H + k];
        Wt2[i] = W2[o * H + k];
    }
}

// ---------------- bucket histogram (196 buckets of 256 dst nodes) ----------------
__global__ void bucket_hist(const int* __restrict__ dst, int* __restrict__ bktcnt, int E) {
    __shared__ int cnt[NBKT];
    const int chunk = (E + gridDim.x - 1) / gridDim.x;
    const int e0 = blockIdx.x * chunk;
    const int e1 = min(e0 + chunk, E);
    for (int i = threadIdx.x; i < NBKT; i += 256) cnt[i] = 0;
    __syncthreads();
    for (int e = e0 + threadIdx.x; e < e1; e += 256) atomicAdd(&cnt[dst[e] >> 8], 1);
    __syncthreads();
    for (int i = threadIdx.x; i < NBKT; i += 256)
        if (cnt[i]) atomicAdd(&bktcnt[i], cnt[i]);
}

// ---------------- exclusive scan over 196 bucket counts (1 block) ----------------
__global__ void bucket_scan(const int* __restrict__ bktcnt, int* __restrict__ bb,
                            int* __restrict__ bcur, int E) {
    __shared__ int s[256];
    int v = (threadIdx.x < NBKT) ? bktcnt[threadIdx.x] : 0;
    s[threadIdx.x] = v;
    __syncthreads();
    for (int off = 1; off < 256; off <<= 1) {
        int t = (threadIdx.x >= off) ? s[threadIdx.x - off] : 0;
        __syncthreads();
        s[threadIdx.x] += t;
        __syncthreads();
    }
    if (threadIdx.x < NBKT) {
        int base = s[threadIdx.x] - v;
        bb[threadIdx.x] = base;
        bcur[threadIdx.x] = base;
    }
    if (threadIdx.x == 0) bb[NBKT] = E;
}

// ---------------- stage edges bucket-contiguous ----------------
__global__ void bin_edges(const int* __restrict__ src, const int* __restrict__ dst,
                          int* __restrict__ bcur, unsigned int* __restrict__ staged, int E) {
    __shared__ int cnt[NBKT];
    __shared__ int offs[NBKT];
    const int chunk = (E + gridDim.x - 1) / gridDim.x;
    const int e0 = blockIdx.x * chunk;
    const int e1 = min(e0 + chunk, E);
    for (int i = threadIdx.x; i < NBKT; i += 256) cnt[i] = 0;
    __syncthreads();
    for (int e = e0 + threadIdx.x; e < e1; e += 256) atomicAdd(&cnt[dst[e] >> 8], 1);
    __syncthreads();
    for (int i = threadIdx.x; i < NBKT; i += 256) {
        int c = cnt[i];
        offs[i] = c ? atomicAdd(&bcur[i], c) : 0;
        cnt[i] = 0;
    }
    __syncthreads();
    for (int e = e0 + threadIdx.x; e < e1; e += 256) {
        int d = dst[e];
        int bkt = d >> 8;
        int idx = atomicAdd(&cnt[bkt], 1);
        staged[offs[bkt] + idx] = (unsigned int)src[e] | ((unsigned int)(d & 255) << 16);
    }
}

// ---------------- per-bucket: node counts -> row_start/dinv + CSR scatter ----------------
__global__ void csr_build(const unsigned int* __restrict__ staged, const int* __restrict__ bb,
                          int* __restrict__ row_start, float* __restrict__ dinv,
                          int* __restrict__ csr_src, int n, int E) {
    __shared__ int cnt[256];
    __shared__ int loc[256];
    __shared__ int cur[256];
    const int b = blockIdx.x;
    cnt[threadIdx.x] = 0;
    __syncthreads();
    const int e0 = bb[b], e1 = bb[b + 1];
    for (int e = e0 + threadIdx.x; e < e1; e += 256)
        atomicAdd(&cnt[(staged[e] >> 16) & 255], 1);
    __syncthreads();
    int v = cnt[threadIdx.x];
    loc[threadIdx.x] = v;
    __syncthreads();
    for (int off = 1; off < 256; off <<= 1) {
        int t = (threadIdx.x >= off) ? loc[threadIdx.x - off] : 0;
        __syncthreads();
        loc[threadIdx.x] += t;
        __syncthreads();
    }
    const int start = e0 + loc[threadIdx.x] - v;  // exclusive
    const int node = b * 256 + threadIdx.x;
    if (node < n) {
        row_start[node] = start;
        dinv[node] = rsqrtf((float)v + 1.0f);
    }
    if (node == n) row_start[n] = E;
    cur[threadIdx.x] = start;
    __syncthreads();
    for (int e = e0 + threadIdx.x; e < e1; e += 256) {
        unsigned int u = staged[e];
        int j = atomicAdd(&cur[(u >> 16) & 255], 1);
        csr_src[j] = (int)(u & 0xFFFFu);
    }
}

// ---------------- tiled matmul: out = relu_bn(x) @ W^T, scaled by dinv[row] ----------------
// BN stats for the input come as raw slot partials (folded reduce_slots: each
// block redundantly reduces the 32KB slots array -> st_s[128] in LDS).
// Epilogue scales each output row by dinv[row] so gcn_gather needs NO per-edge
// dinv load: out = dinv[d]*(sum h'[src] + h'[d]) + bias with h' = h*dinv[row].
template <int K>
__global__ __launch_bounds__(256, 4) void matmul_tile(const float* __restrict__ x,
                                                      const float* __restrict__ Wtg,
                                                      const float* __restrict__ slots,
                                                      const float* __restrict__ gamma,
                                                      const float* __restrict__ beta,
                                                      const float* __restrict__ dinv,
                                                      float* __restrict__ out, int n) {
    __shared__ float Xs[64 * 68];
    __shared__ float Ws[64 * 64];
    __shared__ __align__(16) float st_s[128];
    const int base = blockIdx.x * 64;
    const int q = threadIdx.x >> 4;         // 0..15
    const int co = (threadIdx.x & 15) * 4;  // 0..60

    if (slots) {
        if (threadIdx.x < 128) {
            float s0 = 0.f, s1 = 0.f, s2 = 0.f, s3 = 0.f;
            for (int k = 0; k < 64; k += 4) {
                s0 += slots[(k + 0) * 128 + threadIdx.x];
                s1 += slots[(k + 1) * 128 + threadIdx.x];
                s2 += slots[(k + 2) * 128 + threadIdx.x];
                s3 += slots[(k + 3) * 128 + threadIdx.x];
            }
            st_s[threadIdx.x] = (s0 + s1) + (s2 + s3);
        }
        __syncthreads();
    }

    float4 a0 = make_float4(0.f, 0.f, 0.f, 0.f);
    float4 a1 = a0, a2 = a0, a3 = a0;

    for (int kc = 0; kc < K; kc += 64) {
        if (kc) __syncthreads();
        for (int i = threadIdx.x; i < 64 * 64; i += 256) Ws[i] = Wtg[kc * 64 + i];
        {
            const int kq = (threadIdx.x & 15) * 4;
            float4 sc = make_float4(1.f, 1.f, 1.f, 1.f);
            float4 sh = make_float4(0.f, 0.f, 0.f, 0.f);
            if (slots) {
                int kk = kc + kq;
                float4 s = *(const float4*)&st_s[kk];
                float4 ss = *(const float4*)&st_s[64 + kk];
                float4 gm = *(const float4*)&gamma[kk];
                float4 bt = *(const float4*)&beta[kk];
                float mx = s.x * INV_N, my = s.y * INV_N, mz = s.z * INV_N, mw = s.w * INV_N;
                sc.x = gm.x * rsqrtf(ss.x * INV_N - mx * mx + BN_EPS);
                sc.y = gm.y * rsqrtf(ss.y * INV_N - my * my + BN_EPS);
                sc.z = gm.z * rsqrtf(ss.z * INV_N - mz * mz + BN_EPS);
                sc.w = gm.w * rsqrtf(ss.w * INV_N - mw * mw + BN_EPS);
                sh.x = bt.x - mx * sc.x;
                sh.y = bt.y - my * sc.y;
                sh.z = bt.z - mz * sc.z;
                sh.w = bt.w - mw * sc.w;
            }
            for (int j = 0; j < 4; ++j) {
                int r = (threadIdx.x >> 4) + j * 16;
                int row = base + r;
                float4 v = make_float4(0.f, 0.f, 0.f, 0.f);
                if (row < n) v = *(const float4*)&x[(size_t)row * K + kc + kq];
                if (slots) {
                    v.x = fmaxf(v.x * sc.x + sh.x, 0.f);
                    v.y = fmaxf(v.y * sc.y + sh.y, 0.f);
                    v.z = fmaxf(v.z * sc.z + sh.z, 0.f);
                    v.w = fmaxf(v.w * sc.w + sh.w, 0.f);
                }
                *(float4*)&Xs[r * 68 + kq] = v;
            }
        }
        __syncthreads();

#pragma unroll 2
        for (int k = 0; k < 64; k += 4) {
            float4 x0 = *(const float4*)&Xs[(q + 0) * 68 + k];
            float4 x1 = *(const float4*)&Xs[(q + 16) * 68 + k];
            float4 x2 = *(const float4*)&Xs[(q + 32) * 68 + k];
            float4 x3 = *(const float4*)&Xs[(q + 48) * 68 + k];
            float4 w0 = *(const float4*)&Ws[(k + 0) * 64 + co];
            float4 w1 = *(const float4*)&Ws[(k + 1) * 64 + co];
            float4 w2 = *(const float4*)&Ws[(k + 2) * 64 + co];
            float4 w3 = *(const float4*)&Ws[(k + 3) * 64 + co];

            a0.x += x0.x * w0.x + x0.y * w1.x + x0.z * w2.x + x0.w * w3.x;
            a0.y += x0.x * w0.y + x0.y * w1.y + x0.z * w2.y + x0.w * w3.y;
            a0.z += x0.x * w0.z + x0.y * w1.z + x0.z * w2.z + x0.w * w3.z;
            a0.w += x0.x * w0.w + x0.y * w1.w + x0.z * w2.w + x0.w * w3.w;

            a1.x += x1.x * w0.x + x1.y * w1.x + x1.z * w2.x + x1.w * w3.x;
            a1.y += x1.x * w0.y + x1.y * w1.y + x1.z * w2.y + x1.w * w3.y;
            a1.z += x1.x * w0.z + x1.y * w1.z + x1.z * w2.z + x1.w * w3.z;
            a1.w += x1.x * w0.w + x1.y * w1.w + x1.z * w2.w + x1.w * w3.w;

            a2.x += x2.x * w0.x + x2.y * w1.x + x2.z * w2.x + x2.w * w3.x;
            a2.y += x2.x * w0.y + x2.y * w1.y + x2.z * w2.y + x2.w * w3.y;
            a2.z += x2.x * w0.z + x2.y * w1.z + x2.z * w2.z + x2.w * w3.z;
            a2.w += x2.x * w0.w + x2.y * w1.w + x2.z * w2.w + x2.w * w3.w;

            a3.x += x3.x * w0.x + x3.y * w1.x + x3.z * w2.x + x3.w * w3.x;
            a3.y += x3.x * w0.y + x3.y * w1.y + x3.z * w2.y + x3.w * w3.y;
            a3.z += x3.x * w0.z + x3.y * w1.z + x3.z * w2.z + x3.w * w3.z;
            a3.w += x3.x * w0.w + x3.y * w1.w + x3.z * w2.w + x3.w * w3.w;
        }
    }

    int r0 = base + q;
    if (r0 < n) {
        float dv = dinv[r0];
        a0.x *= dv; a0.y *= dv; a0.z *= dv; a0.w *= dv;
        *(float4*)&out[(size_t)r0 * H + co] = a0;
    }
    if (r0 + 16 < n) {
        float dv = dinv[r0 + 16];
        a1.x *= dv; a1.y *= dv; a1.z *= dv; a1.w *= dv;
        *(float4*)&out[(size_t)(r0 + 16) * H + co] = a1;
    }
    if (r0 + 32 < n) {
        float dv = dinv[r0 + 32];
        a2.x *= dv; a2.y *= dv; a2.z *= dv; a2.w *= dv;
        *(float4*)&out[(size_t)(r0 + 32) * H + co] = a2;
    }
    if (r0 + 48 < n) {
        float dv = dinv[r0 + 48];
        a3.x *= dv; a3.y *= dv; a3.z *= dv; a3.w *= dv;
        *(float4*)&out[(size_t)(r0 + 48) * H + co] = a3;
    }
}

// ---------------- fused GCN aggregation + BN-stats (float4 lanes) ----------------
// Lane = (e in 0..3, q in 0..15): one wave gathers 4 edges per dwordx4 load
// (1 KB/instr vs 256B before) and needs no per-edge dinv (baked into h by the
// matmul epilogue). Per 4 edges: 1 csr load + 1 h load + 4 VALU adds.
// Cross-e totals via 2x shfl_xor; stats via LDS + 64-way-spread slot atomics.
__global__ void gcn_gather(const float* __restrict__ h, const int* __restrict__ row_start,
                           const int* __restrict__ csr_src, const float* __restrict__ dinv,
                           const float* __restrict__ bias, float* __restrict__ out,
                           float* __restrict__ slots, int n) {
    const int wv = threadIdx.x >> 6;
    const int lane = threadIdx.x & 63;
    const int e = lane >> 4;         // edge slot 0..3
    const int f4 = (lane & 15) * 4;  // feature quad
    const int d0 = blockIdx.x * 8 + wv * 2;
    float4 scc = make_float4(0.f, 0.f, 0.f, 0.f);
    float4 qcc = scc;
    if (d0 < n) {
        const int d1 = d0 + 1;  // n even -> d1 < n
        const int rA = row_start[d0];
        const int rM = row_start[d1];
        const int rE = row_start[d1 + 1];
        const float dA = dinv[d0], dB = dinv[d1];
        const float4 selfA = *(const float4*)&h[(size_t)d0 * H + f4];
        const float4 selfB = *(const float4*)&h[(size_t)d1 * H + f4];
        const float4 bq = *(const float4*)&bias[f4];
        float4 a0 = make_float4(0.f, 0.f, 0.f, 0.f), a1 = a0, b0 = a0, b1 = a0;
        int jA = rA + e;
        int jB = rM + e;
        while (jA + 4 < rM && jB + 4 < rE) {
            int sA0 = csr_src[jA], sA1 = csr_src[jA + 4];
            int sB0 = csr_src[jB], sB1 = csr_src[jB + 4];
            f4acc(a0, *(const float4*)&h[(size_t)sA0 * H + f4]);
            f4acc(a1, *(const float4*)&h[(size_t)sA1 * H + f4]);
            f4acc(b0, *(const float4*)&h[(size_t)sB0 * H + f4]);
            f4acc(b1, *(const float4*)&h[(size_t)sB1 * H + f4]);
            jA += 8;
            jB += 8;
        }
        while (jA + 4 < rM) {
            int s0 = csr_src[jA], s1 = csr_src[jA + 4];
            f4acc(a0, *(const float4*)&h[(size_t)s0 * H + f4]);
            f4acc(a1, *(const float4*)&h[(size_t)s1 * H + f4]);
            jA += 8;
        }
        if (jA < rM) {
            int s = csr_src[jA];
            f4acc(a0, *(const float4*)&h[(size_t)s * H + f4]);
        }
        while (jB + 4 < rE) {
            int s0 = csr_src[jB], s1 = csr_src[jB + 4];
            f4acc(b0, *(const float4*)&h[(size_t)s0 * H + f4]);
            f4acc(b1, *(const float4*)&h[(size_t)s1 * H + f4]);
            jB += 8;
        }
        if (jB < rE) {
            int s = csr_src[jB];
            f4acc(b0, *(const float4*)&h[(size_t)s * H + f4]);
        }
        f4acc(a0, a1);
        f4acc(b0, b1);
        // cross-e reduce: lane bits 4,5 select e -> xor 16 then 32
        a0.x += __shfl_xor(a0.x, 16); a0.x += __shfl_xor(a0.x, 32);
        a0.y += __shfl_xor(a0.y, 16); a0.y += __shfl_xor(a0.y, 32);
        a0.z += __shfl_xor(a0.z, 16); a0.z += __shfl_xor(a0.z, 32);
        a0.w += __shfl_xor(a0.w, 16); a0.w += __shfl_xor(a0.w, 32);
        b0.x += __shfl_xor(b0.x, 16); b0.x += __shfl_xor(b0.x, 32);
        b0.y += __shfl_xor(b0.y, 16); b0.y += __shfl_xor(b0.y, 32);
        b0.z += __shfl_xor(b0.z, 16); b0.z += __shfl_xor(b0.z, 32);
        b0.w += __shfl_xor(b0.w, 16); b0.w += __shfl_xor(b0.w, 32);
        float4 vA, vB;
        vA.x = bq.x + dA * (selfA.x + a0.x);
        vA.y = bq.y + dA * (selfA.y + a0.y);
        vA.z = bq.z + dA * (selfA.z + a0.z);
        vA.w = bq.w + dA * (selfA.w + a0.w);
        vB.x = bq.x + dB * (selfB.x + b0.x);
        vB.y = bq.y + dB * (selfB.y + b0.y);
        vB.z = bq.z + dB * (selfB.z + b0.z);
        vB.w = bq.w + dB * (selfB.w + b0.w);
        if (e < 2) {
            float4 vS;
            vS.x = e ? vB.x : vA.x;
            vS.y = e ? vB.y : vA.y;
            vS.z = e ? vB.z : vA.z;
            vS.w = e ? vB.w : vA.w;
            *(float4*)&out[(size_t)(d0 + e) * H + f4] = vS;
        }
        scc.x = vA.x + vB.x; scc.y = vA.y + vB.y;
        scc.z = vA.z + vB.z; scc.w = vA.w + vB.w;
        qcc.x = vA.x * vA.x + vB.x * vB.x;
        qcc.y = vA.y * vA.y + vB.y * vB.y;
        qcc.z = vA.z * vA.z + vB.z * vB.z;
        qcc.w = vA.w * vA.w + vB.w * vB.w;
    }
    __shared__ float4 reds[64], redq[64];
    if (e == 0) {
        reds[wv * 16 + (lane & 15)] = scc;
        redq[wv * 16 + (lane & 15)] = qcc;
    }
    __syncthreads();
    const int tid = threadIdx.x;
    if (tid < 32) {
        const int t = tid & 15;
        const float4* rp = (tid < 16) ? reds : redq;
        float4 r0 = rp[t], r1 = rp[16 + t], r2 = rp[32 + t], r3 = rp[48 + t];
        float4 s;
        s.x = (r0.x + r1.x) + (r2.x + r3.x);
        s.y = (r0.y + r1.y) + (r2.y + r3.y);
        s.z = (r0.z + r1.z) + (r2.z + r3.z);
        s.w = (r0.w + r1.w) + (r2.w + r3.w);
        float* slot = slots + (blockIdx.x & 63) * 128 + (tid < 16 ? 0 : 64) + t * 4;
        atomicAdd(&slot[0], s.x);
        atomicAdd(&slot[1], s.y);
        atomicAdd(&slot[2], s.z);
        atomicAdd(&slot[3], s.w);
    }
}

// ---------------- global mean pool (fuses slot-reduce + last BN finalize+apply+ReLU) -----
#define PROWS 16
__global__ void pool_seg(const float* __restrict__ h, const float* __restrict__ slots,
                         const float* __restrict__ gamma, const float* __restrict__ beta,
                         const int* __restrict__ batch, float* __restrict__ pool,
                         float* __restrict__ cnt, int n) {
    __shared__ __align__(16) float st_s[128];
    if (threadIdx.x < 128) {
        float s0 = 0.f, s1 = 0.f, s2 = 0.f, s3 = 0.f;
        for (int k = 0; k < 64; k += 4) {
            s0 += slots[(k + 0) * 128 + threadIdx.x];
            s1 += slots[(k + 1) * 128 + threadIdx.x];
            s2 += slots[(k + 2) * 128 + threadIdx.x];
            s3 += slots[(k + 3) * 128 + threadIdx.x];
        }
        st_s[threadIdx.x] = (s0 + s1) + (s2 + s3);
    }
    __syncthreads();
    int wave = blockIdx.x * 4 + (threadIdx.x >> 6);
    int c = threadIdx.x & 63;
    int r0 = wave * PROWS;
    if (r0 >= n) return;
    int r1 = min(r0 + PROWS, n);
    float mean = st_s[c] * INV_N;
    float var = st_s[64 + c] * INV_N - mean * mean;
    float sc = gamma[c] * rsqrtf(var + BN_EPS);
    float sh = beta[c] - mean * sc;
    int cur = batch[r0];
    float acc = 0.f;
    int nlocal = 0;
    for (int r = r0; r < r1; ++r) {
        int g = batch[r];
        if (g != cur) {
            atomicAdd(&pool[cur * H + c], acc);
            if (c == 0) atomicAdd(&cnt[cur], (float)nlocal);
            cur = g;
            acc = 0.f;
            nlocal = 0;
        }
        acc += fmaxf(h[(size_t)r * H + c] * sc + sh, 0.f);
        ++nlocal;
    }
    atomicAdd(&pool[cur * H + c], acc);
    if (c == 0) atomicAdd(&cnt[cur], (float)nlocal);
}

// ---------------- final MLP ----------------
__global__ void final_mlp(const float* __restrict__ pool, const float* __restrict__ cnt,
                          const float* __restrict__ l1w, const float* __restrict__ l1b,
                          const float* __restrict__ l2w, const float* __restrict__ l2b,
                          float* __restrict__ out) {
    int tid = blockIdx.x * 256 + threadIdx.x;
    int g = tid >> 5;
    int j = tid & 31;
    if (g >= NG) return;
    float inv = 1.0f / fmaxf(cnt[g], 1.0f);
    float s = l1b[j];
    for (int k = 0; k < H; ++k) s += pool[g * H + k] * inv * l1w[j * H + k];
    float v = fmaxf(s, 0.0f) * l2w[j];
    for (int off = 16; off > 0; off >>= 1) v += __shfl_down(v, off, 32);
    if (j == 0) out[g] = v + l2b[0];
}

extern "C" void kernel_launch(void* const* d_in, const int* in_sizes, int n_in,
                              void* d_out, int out_size, void* d_ws, size_t ws_size,
                              hipStream_t stream) {
    const float* x = (const float*)d_in[0];
    const int* ei = (const int*)d_in[1];
    const int* batch = (const int*)d_in[2];
    const float* W[3] = {(const float*)d_in[3], (const float*)d_in[7], (const float*)d_in[11]};
    const float* b[3] = {(const float*)d_in[4], (const float*)d_in[8], (const float*)d_in[12]};
    const float* g[3] = {(const float*)d_in[5], (const float*)d_in[9], (const float*)d_in[13]};
    const float* be[3] = {(const float*)d_in[6], (const float*)d_in[10], (const float*)d_in[14]};
    const float* l1w = (const float*)d_in[15];
    const float* l1b = (const float*)d_in[16];
    const float* l2w = (const float*)d_in[17];
    const float* l2b = (const float*)d_in[18];
    float* out = (float*)d_out;

    const int* src = ei;
    const int* dst = ei + NE;

    // ---- workspace layout (4-byte units) ----
    char* wsb = (char*)d_ws;
    size_t off = 0;
    auto alloc = [&](size_t elems) {
        void* p = wsb + off;
        off += elems * 4;
        return p;
    };
    float* dinv = (float*)alloc(50048);
    float* bufA = (float*)alloc((size_t)NN * H);
    float* bufB = (float*)alloc((size_t)NN * H);
    float* slots[3] = {(float*)alloc(64 * 128), (float*)alloc(64 * 128), (float*)alloc(64 * 128)};
    float* pool = (float*)alloc(NG * H);
    float* cnt = (float*)alloc(64);
    float* Wt[3] = {(float*)alloc(FIN * 64), (float*)alloc(H * 64), (float*)alloc(H * 64)};
    int* row_start = (int*)alloc(50112);   // NN+1
    int* bktcnt = (int*)alloc(256);        // NBKT
    int* bb = (int*)alloc(256);            // bucket bases (NBKT+1)
    int* bcur = (int*)alloc(256);          // bucket cursors
    unsigned int* staged = (unsigned int*)alloc(NE);
    int* csr_src = (int*)alloc(NE);

    // ---- setup + binned CSR build ----
    setup_misc<<<32, 256, 0, stream>>>(W[0], W[1], W[2], Wt[0], Wt[1], Wt[2], slots[0], slots[1],
                                       slots[2], pool, bktcnt);
    bucket_hist<<<256, 256, 0, stream>>>(dst, bktcnt, NE);
    bucket_scan<<<1, 256, 0, stream>>>(bktcnt, bb, bcur, NE);
    bin_edges<<<256, 256, 0, stream>>>(src, dst, bcur, staged, NE);
    csr_build<<<NBKT, 256, 0, stream>>>(staged, bb, row_start, dinv, csr_src, NN, NE);

    const int grid_mm = (NN + 63) / 64;    // 782
    const int grid_gather = (NN + 7) / 8;  // 6250

    // ---- 3 GCN layers (BN of layer L-1 fused into layer L's X staging, slot
    //      reduce folded into the consumer; matmul output pre-scaled by dinv) ----
    for (int L = 0; L < 3; ++L) {
        if (L == 0)
            matmul_tile<FIN><<<grid_mm, 256, 0, stream>>>(x, Wt[0], nullptr, nullptr, nullptr,
                                                          dinv, bufA, NN);
        else
            matmul_tile<H><<<grid_mm, 256, 0, stream>>>(bufB, Wt[L], slots[L - 1], g[L - 1],
                                                        be[L - 1], dinv, bufA, NN);
        gcn_gather<<<grid_gather, 256, 0, stream>>>(bufA, row_start, csr_src, dinv, b[L], bufB,
                                                    slots[L], NN);
    }

    // ---- global mean pool (fused BN of layer 2 + slot reduce) + MLP head ----
    const int pool_waves = (NN + PROWS - 1) / PROWS;  // 3125
    pool_seg<<<(pool_waves + 3) / 4, 256, 0, stream>>>(bufB, slots[2], g[2], be[2], batch, pool,
                                                       cnt, NN);
    final_mlp<<<8, 256, 0, stream>>>(pool, cnt, l1w, l1b, l2w, l2b, out);
}